// Round 5
// baseline (132.403 us; speedup 1.0000x reference)
//
#include <hip/hip_runtime.h>
#include <math.h>

#define NELEM   262144            // 4*64*32*32
#define NW      36864             // 64*64*3*3
#define PIMG    1296              // 36*36 padded image stride per (b,c)
#define PADN    331776            // 4*64*36*36
#define NBORD   295936            // 4*64*34*34
#define EPS_BN  1e-5f
#define QSCALE  65536.0f
#define QBIAS_F (16.0f * 65536.0f + 0.5f)
#define QB_U    1048576u          // quantized 0.0
#define QINV    (1.0f / 65536.0f)

__device__ __forceinline__ unsigned sad_acc(unsigned a, unsigned b, unsigned acc) {
    asm("v_sad_u32 %0, %1, %2, %0" : "+v"(acc) : "v"(a), "v"(b));
    return acc;
}

// ---------------------------------------------------------------------------
// prep (merged): one NBORD pass writes qxp (full padded 34x34 region) AND
// qout1p's halo; then weight quant (w1,w2), bn2 constants, sbuf zero.
// ---------------------------------------------------------------------------
__global__ __launch_bounds__(256) void prep_kernel(
    const float* __restrict__ x,
    const float* __restrict__ g1, const float* __restrict__ b1,
    const float* __restrict__ m1, const float* __restrict__ v1,
    const float* __restrict__ w1,
    const float* __restrict__ g2, const float* __restrict__ b2,
    const float* __restrict__ m2, const float* __restrict__ v2,
    const float* __restrict__ w2,
    unsigned* __restrict__ qxp, unsigned* __restrict__ qout1p,
    unsigned* __restrict__ qw1, unsigned* __restrict__ qw2,
    float* __restrict__ bn2c, float* __restrict__ sbuf)
{
    int i = blockIdx.x * 256 + threadIdx.x;
    if (i < NBORD) {
        int bc  = i / 1156;                       // b*64+c
        int rc  = i - bc * 1156;
        int r   = rc / 34;
        int col = rc - r * 34;
        bool interior = (r > 0 && r < 33 && col > 0 && col < 33);
        unsigned q = QB_U;
        if (interior) {
            int c = bc & 63;
            float inv = g1[c] * rsqrtf(v1[c] + EPS_BN);
            float bet = b1[c] - m1[c] * inv;
            float a = fmaxf(fmaf(x[(bc * 32 + (r - 1)) * 32 + (col - 1)], inv, bet), 0.f);
            q = (unsigned)fmaf(a, QSCALE, QBIAS_F);
        }
        int pidx = bc * PIMG + r * 36 + col;
        qxp[pidx] = q;
        if (!interior) qout1p[pidx] = QB_U;       // adder1 fills the interior
        return;
    }
    int k = i - NBORD;
    if (k < NW) { qw1[k] = (unsigned)fmaf(w1[k], QSCALE, QBIAS_F); return; }
    int l = k - NW;
    if (l < NW) { qw2[l] = (unsigned)fmaf(w2[l], QSCALE, QBIAS_F); return; }
    int m = l - NW;
    if (m < 64) {
        float inv = g2[m] * rsqrtf(v2[m] + EPS_BN);
        bn2c[m]      = -inv * QINV;
        bn2c[m + 64] = b2[m] - m2[m] * inv;
        return;
    }
    int s = m - 64;
    if (s >= 0 && s < 256) sbuf[s] = 0.f;
}

// ---------------------------------------------------------------------------
// Adder2d, barrier-free, 2-deep channel-pipelined patch loads from the padded
// global buffer. Grid 1024 = b(4) x og(32: 2 outputs) x sp(8: 4-row strips).
// 256 threads: pos=t&15 (y_i=pos>>2, x0=(pos&3)*8), cq=t>>4 -> 4 channels.
// MODE 0: writes quant(relu(bn2(-acc))) into padded qout (idempotent).
// MODE 1: writes float out2 + SE spatial-sum atomics into sbuf.
// ---------------------------------------------------------------------------
template<int MODE>
__global__ __launch_bounds__(256, 4) void adder_kernel(
    const unsigned* __restrict__ qsrc, const unsigned* __restrict__ qw,
    const float* __restrict__ bn2c,
    unsigned* __restrict__ qout, float* __restrict__ fout,
    float* __restrict__ sbuf)
{
    __shared__ unsigned wlds[2][64][12];     // 6144 B
    __shared__ unsigned red[16][16][16];     // 16384 B

    const int blk = blockIdx.x;
    const int sp  = blk & 7;
    const int og  = (blk >> 3) & 31;
    const int b   = blk >> 8;
    const int t   = threadIdx.x;
    const int pos = t & 15;
    const int cq  = t >> 4;
    const int y_i = pos >> 2;
    const int x0  = (pos & 3) * 8;

    for (int i = t; i < 1152; i += 256) {
        int o_i = i / 576;
        int rem = i - o_i * 576;
        int c   = rem / 9;
        int kk  = rem - c * 9;
        wlds[o_i][c][kk] = qw[(og * 2 + o_i) * 576 + c * 9 + kk];
    }
    __syncthreads();

    unsigned acc[2][8];
#pragma unroll
    for (int oo = 0; oo < 2; ++oo)
#pragma unroll
        for (int xi = 0; xi < 8; ++xi) acc[oo][xi] = 0u;

    const unsigned* base = qsrc + (size_t)(b * 64 + cq * 4) * PIMG
                                + (sp * 4 + y_i) * 36 + x0;

    unsigned p[2][3][12];
    // prologue: load channel 0's patch
#pragma unroll
    for (int r = 0; r < 3; ++r) {
        uint4 a0 = *reinterpret_cast<const uint4*>(base + r * 36);
        uint4 a1 = *reinterpret_cast<const uint4*>(base + r * 36 + 4);
        uint4 a2 = *reinterpret_cast<const uint4*>(base + r * 36 + 8);
        p[0][r][0] = a0.x; p[0][r][1]  = a0.y; p[0][r][2]  = a0.z; p[0][r][3]  = a0.w;
        p[0][r][4] = a1.x; p[0][r][5]  = a1.y; p[0][r][6]  = a1.z; p[0][r][7]  = a1.w;
        p[0][r][8] = a2.x; p[0][r][9]  = a2.y; p[0][r][10] = a2.z; p[0][r][11] = a2.w;
    }

#pragma unroll
    for (int j = 0; j < 4; ++j) {
        // prefetch next channel's patch (issued before current channel's sads;
        // compiler waits at vmcnt(9), not vmcnt(0))
        if (j < 3) {
            const unsigned* pn = base + (j + 1) * PIMG;
            const int nb = (j + 1) & 1;
#pragma unroll
            for (int r = 0; r < 3; ++r) {
                uint4 a0 = *reinterpret_cast<const uint4*>(pn + r * 36);
                uint4 a1 = *reinterpret_cast<const uint4*>(pn + r * 36 + 4);
                uint4 a2 = *reinterpret_cast<const uint4*>(pn + r * 36 + 8);
                p[nb][r][0] = a0.x; p[nb][r][1]  = a0.y; p[nb][r][2]  = a0.z; p[nb][r][3]  = a0.w;
                p[nb][r][4] = a1.x; p[nb][r][5]  = a1.y; p[nb][r][6]  = a1.z; p[nb][r][7]  = a1.w;
                p[nb][r][8] = a2.x; p[nb][r][9]  = a2.y; p[nb][r][10] = a2.z; p[nb][r][11] = a2.w;
            }
        }
        const int c  = cq * 4 + j;
        const int cb = j & 1;
#pragma unroll
        for (int oo = 0; oo < 2; ++oo) {   // serial per-oo: only 9 weight regs live
            uint4 wa = *reinterpret_cast<const uint4*>(&wlds[oo][c][0]);
            uint4 wb = *reinterpret_cast<const uint4*>(&wlds[oo][c][4]);
            unsigned w8 = wlds[oo][c][8];
            unsigned wv[9] = {wa.x, wa.y, wa.z, wa.w,
                              wb.x, wb.y, wb.z, wb.w, w8};
#pragma unroll
            for (int kh = 0; kh < 3; ++kh)
#pragma unroll
                for (int kw = 0; kw < 3; ++kw) {
                    unsigned ww = wv[kh * 3 + kw];
#pragma unroll
                    for (int xi = 0; xi < 8; ++xi)
                        acc[oo][xi] = sad_acc(p[cb][kh][xi + kw], ww, acc[oo][xi]);
                }
        }
    }

    // ---- cq reduction via LDS ----
    {
        unsigned* dst = &red[cq][pos][0];
        *reinterpret_cast<uint4*>(dst + 0)  = make_uint4(acc[0][0], acc[0][1], acc[0][2], acc[0][3]);
        *reinterpret_cast<uint4*>(dst + 4)  = make_uint4(acc[0][4], acc[0][5], acc[0][6], acc[0][7]);
        *reinterpret_cast<uint4*>(dst + 8)  = make_uint4(acc[1][0], acc[1][1], acc[1][2], acc[1][3]);
        *reinterpret_cast<uint4*>(dst + 12) = make_uint4(acc[1][4], acc[1][5], acc[1][6], acc[1][7]);
    }
    __syncthreads();

    const int oo2 = t >> 7;
    const int s   = t & 127;
    const int yy2 = s >> 5;
    const int xx2 = s & 31;
    const int pp  = yy2 * 4 + (xx2 >> 3);
    const int z   = (oo2 << 3) | (xx2 & 7);
    unsigned total = 0;
#pragma unroll
    for (int q = 0; q < 16; ++q) total += red[q][pp][z];

    const int o    = og * 2 + oo2;
    const int gy   = sp * 4 + yy2;
    const float accf = (float)total;

    if (MODE == 0) {
        float a2 = fmaxf(fmaf(accf, bn2c[o], bn2c[o + 64]), 0.f);
        qout[(size_t)(b * 64 + o) * PIMG + (gy + 1) * 36 + (xx2 + 1)] =
            (unsigned)fmaf(a2, QSCALE, QBIAS_F);
    } else {
        float v = -accf * QINV;
        fout[((b * 64 + o) * 32 + gy) * 32 + xx2] = v;
        float sum = v;
#pragma unroll
        for (int off = 32; off > 0; off >>= 1)
            sum += __shfl_down(sum, off, 64);
        if ((t & 63) == 0) atomicAdd(&sbuf[b * 64 + o], sum);
    }
}

// ---------------------------------------------------------------------------
// SE gate + apply + shortcut. 256 blocks (one per b,o image) x 256 threads.
// ---------------------------------------------------------------------------
__global__ __launch_bounds__(256) void gate_kernel(
    const float* __restrict__ out2, const float* __restrict__ x,
    const float* __restrict__ sbuf,
    const float* __restrict__ fc1w, const float* __restrict__ fc1b,
    const float* __restrict__ fc2w, const float* __restrict__ fc2b,
    float* __restrict__ out)
{
    const int bo = blockIdx.x;
    const int b  = bo >> 6;
    const int o  = bo & 63;
    const int t  = threadIdx.x;

    __shared__ float ss[64];
    if (t < 64) ss[t] = sbuf[b * 64 + t] * (1.f / 1024.f);
    __syncthreads();

    float h[4];
#pragma unroll
    for (int j = 0; j < 4; ++j) {
        float a = fc1b[j];
#pragma unroll
        for (int c = 0; c < 64; ++c) a += ss[c] * fc1w[j * 64 + c];
        h[j] = fmaxf(a, 0.f);
    }
    float zz = fc2b[o];
#pragma unroll
    for (int j = 0; j < 4; ++j) zz += h[j] * fc2w[o * 4 + j];
    float g = 1.f / (1.f + __expf(-zz));

    const int base = bo * 1024 + t * 4;
    float4 v  = *reinterpret_cast<const float4*>(out2 + base);
    float4 xv = *reinterpret_cast<const float4*>(x + base);
    float4 r;
    r.x = v.x * g + xv.x;
    r.y = v.y * g + xv.y;
    r.z = v.z * g + xv.z;
    r.w = v.w * g + xv.w;
    *reinterpret_cast<float4*>(out + base) = r;
}

// ---------------------------------------------------------------------------
extern "C" void kernel_launch(void* const* d_in, const int* in_sizes, int n_in,
                              void* d_out, int out_size, void* d_ws, size_t ws_size,
                              hipStream_t stream)
{
    const float* x    = (const float*)d_in[0];
    const float* bn1g = (const float*)d_in[1];
    const float* bn1b = (const float*)d_in[2];
    const float* bn1m = (const float*)d_in[3];
    const float* bn1v = (const float*)d_in[4];
    const float* w1   = (const float*)d_in[5];
    const float* bn2g = (const float*)d_in[6];
    const float* bn2b = (const float*)d_in[7];
    const float* bn2m = (const float*)d_in[8];
    const float* bn2v = (const float*)d_in[9];
    const float* w2   = (const float*)d_in[10];
    const float* fc1w = (const float*)d_in[11];
    const float* fc1b = (const float*)d_in[12];
    const float* fc2w = (const float*)d_in[13];
    const float* fc2b = (const float*)d_in[14];

    unsigned* ws     = (unsigned*)d_ws;
    unsigned* qxp    = ws;                          // PADN
    unsigned* qout1p = ws + PADN;                   // PADN
    float*    out2   = (float*)(ws + 2 * PADN);     // NELEM
    unsigned* qw1    = ws + 2 * PADN + NELEM;       // NW
    unsigned* qw2    = ws + 2 * PADN + NELEM + NW;  // NW
    float*    bn2c   = (float*)(ws + 2 * PADN + NELEM + 2 * NW);        // 128
    float*    sbuf   = (float*)(ws + 2 * PADN + NELEM + 2 * NW + 128);  // 256

    // segments: NBORD + NW + NW + 64 + 256 = 369,984 -> 1446 blocks
    prep_kernel<<<1446, 256, 0, stream>>>(x, bn1g, bn1b, bn1m, bn1v, w1,
                                          bn2g, bn2b, bn2m, bn2v, w2,
                                          qxp, qout1p, qw1, qw2, bn2c, sbuf);
    // DIAGNOSTIC: adder1 launched 3x (idempotent). dur_R5 - dur_R6 = 2*t_adder1.
    adder_kernel<0><<<1024, 256, 0, stream>>>(qxp, qw1, bn2c, qout1p, nullptr, nullptr);
    adder_kernel<0><<<1024, 256, 0, stream>>>(qxp, qw1, bn2c, qout1p, nullptr, nullptr);
    adder_kernel<0><<<1024, 256, 0, stream>>>(qxp, qw1, bn2c, qout1p, nullptr, nullptr);
    adder_kernel<1><<<1024, 256, 0, stream>>>(qout1p, qw2, nullptr, nullptr, out2, sbuf);
    gate_kernel<<<256, 256, 0, stream>>>(out2, x, sbuf, fc1w, fc1b, fc2w, fc2b,
                                         (float*)d_out);
}

// Round 6
// 109.592 us; speedup vs baseline: 1.2081x; 1.2081x over previous
//
#include <hip/hip_runtime.h>
#include <math.h>

#define NELEM   262144            // 4*64*32*32
#define NPAIRW  18432             // 64 o * 32 pairs * 9
#define PIMG    1296              // 36*36 padded image stride per (b,pair)
#define PPADN   165888            // 4*32*36*36 words
#define NPAIR   147968            // 4*32*34*34
#define EPS_BN  1e-5f
#define QSC     128.0f
#define QBIAS_F 16384.5f          // bias 16384 + 0.5 rounding
#define QZ_W    0x40004000u       // packed quantized zero (16384 | 16384<<16)
#define QINV    (1.0f / 128.0f)

// v_sad_u16: acc += |a.lo-b.lo| + |a.hi-b.hi|  (two terms per instruction)
__device__ __forceinline__ unsigned sad16(unsigned a, unsigned b, unsigned acc) {
    asm("v_sad_u16 %0, %1, %2, %0" : "+v"(acc) : "v"(a), "v"(b));
    return acc;
}

__device__ __forceinline__ unsigned qu(float v) {
    return (unsigned)(int)fmaf(v, QSC, QBIAS_F);
}

// ---------------------------------------------------------------------------
// prep: pair-packed quantized padded input qxp[4][32][36][36] (u16x2 words),
// qout1p halo words, pair-packed weights qw1p/qw2p[o][pair][9], bn2 consts,
// sbuf zero. Segmented elementwise kernel.
// ---------------------------------------------------------------------------
__global__ __launch_bounds__(256) void prep_kernel(
    const float* __restrict__ x,
    const float* __restrict__ g1, const float* __restrict__ b1,
    const float* __restrict__ m1, const float* __restrict__ v1,
    const float* __restrict__ w1,
    const float* __restrict__ g2, const float* __restrict__ b2,
    const float* __restrict__ m2, const float* __restrict__ v2,
    const float* __restrict__ w2,
    unsigned* __restrict__ qxp, unsigned* __restrict__ qout1p,
    unsigned* __restrict__ qw1p, unsigned* __restrict__ qw2p,
    float* __restrict__ bn2c, float* __restrict__ sbuf)
{
    int i = blockIdx.x * 256 + threadIdx.x;
    if (i < NPAIR) {
        int bp  = i / 1156;                       // b*32 + pair
        int rc  = i - bp * 1156;
        int r   = rc / 34;
        int col = rc - r * 34;
        bool interior = (r > 0 && r < 33 && col > 0 && col < 33);
        unsigned q = QZ_W;
        if (interior) {
            int b  = bp >> 5;
            int c0 = (bp & 31) * 2;
            float inv0 = g1[c0] * rsqrtf(v1[c0] + EPS_BN);
            float bet0 = b1[c0] - m1[c0] * inv0;
            float inv1 = g1[c0 + 1] * rsqrtf(v1[c0 + 1] + EPS_BN);
            float bet1 = b1[c0 + 1] - m1[c0 + 1] * inv1;
            int off = (b * 64 + c0) * 1024 + (r - 1) * 32 + (col - 1);
            float a0 = fmaxf(fmaf(x[off],        inv0, bet0), 0.f);
            float a1 = fmaxf(fmaf(x[off + 1024], inv1, bet1), 0.f);
            q = qu(a0) | (qu(a1) << 16);
        }
        int pidx = bp * PIMG + r * 36 + col;
        qxp[pidx] = q;
        if (!interior) qout1p[pidx] = QZ_W;
        return;
    }
    int k = i - NPAIR;
    if (k < NPAIRW) {
        int o   = k / 288;
        int rem = k - o * 288;
        int pr  = rem / 9;
        int kk  = rem - pr * 9;
        int woff = (o * 64 + pr * 2) * 9 + kk;
        qw1p[k] = qu(w1[woff]) | (qu(w1[woff + 9]) << 16);
        return;
    }
    int l = k - NPAIRW;
    if (l < NPAIRW) {
        int o   = l / 288;
        int rem = l - o * 288;
        int pr  = rem / 9;
        int kk  = rem - pr * 9;
        int woff = (o * 64 + pr * 2) * 9 + kk;
        qw2p[l] = qu(w2[woff]) | (qu(w2[woff + 9]) << 16);
        return;
    }
    int m = l - NPAIRW;
    if (m < 64) {
        float inv = g2[m] * rsqrtf(v2[m] + EPS_BN);
        bn2c[m]      = -inv * QINV;               // maps u32 acc -> bn2 pre-act
        bn2c[m + 64] = b2[m] - m2[m] * inv;
        return;
    }
    int s = m - 64;
    if (s >= 0 && s < 256) sbuf[s] = 0.f;
}

// ---------------------------------------------------------------------------
// Adder2d on pair-packed u16 data via v_sad_u16 (2 terms/instr).
// Grid 1024 = b(4) x og(32: 2 outputs) x sp(8: 4-row strips); 256 threads:
// pos=t&15 (y_i=pos>>2, x0=(pos&3)*8), cq=t>>4 -> 2 channel-pairs each.
// Patch loads direct from global (L1/L2-resident), double-buffered; weights
// in LDS; barrier-free main loop. Patch cols 10..11 are loaded-but-unused
// (x0+xi+kw <= 33 < 34), so stride-36 cols 34/35 are never consumed.
// MODE 0: writes quant(relu(bn2(-acc))) as u16 half into packed qout.
// MODE 1: writes float out2 + SE spatial-sum atomics into sbuf.
// ---------------------------------------------------------------------------
template<int MODE>
__global__ __launch_bounds__(256, 4) void adder_kernel(
    const unsigned* __restrict__ qsrc, const unsigned* __restrict__ qwp,
    const float* __restrict__ bn2c,
    unsigned* __restrict__ qout, float* __restrict__ fout,
    float* __restrict__ sbuf)
{
    __shared__ unsigned wlds[2][32][12];     // 3072 B
    __shared__ unsigned red[16][16][16];     // 16384 B

    const int blk = blockIdx.x;
    const int sp  = blk & 7;
    const int og  = (blk >> 3) & 31;
    const int b   = blk >> 8;
    const int t   = threadIdx.x;
    const int pos = t & 15;
    const int cq  = t >> 4;
    const int y_i = pos >> 2;
    const int x0  = (pos & 3) * 8;

    const unsigned* base = qsrc + (size_t)(b * 32 + cq * 2) * PIMG
                                + (sp * 4 + y_i) * 36 + x0;

    // prologue: issue pair-0 patch loads FIRST (latency hides behind staging)
    unsigned p[2][3][12];
#pragma unroll
    for (int r = 0; r < 3; ++r) {
        uint4 a0 = *reinterpret_cast<const uint4*>(base + r * 36);
        uint4 a1 = *reinterpret_cast<const uint4*>(base + r * 36 + 4);
        uint4 a2 = *reinterpret_cast<const uint4*>(base + r * 36 + 8);
        p[0][r][0] = a0.x; p[0][r][1]  = a0.y; p[0][r][2]  = a0.z; p[0][r][3]  = a0.w;
        p[0][r][4] = a1.x; p[0][r][5]  = a1.y; p[0][r][6]  = a1.z; p[0][r][7]  = a1.w;
        p[0][r][8] = a2.x; p[0][r][9]  = a2.y; p[0][r][10] = a2.z; p[0][r][11] = a2.w;
    }

    // weight staging: 2 o x 32 pairs x 9 words
    for (int i = t; i < 576; i += 256) {
        int o_i = i / 288;
        int rem = i - o_i * 288;
        int pr  = rem / 9;
        int kk  = rem - pr * 9;
        wlds[o_i][pr][kk] = qwp[((og * 2 + o_i) * 32 + pr) * 9 + kk];
    }
    __syncthreads();

    unsigned acc[2][8];
#pragma unroll
    for (int oo = 0; oo < 2; ++oo)
#pragma unroll
        for (int xi = 0; xi < 8; ++xi) acc[oo][xi] = 0u;

#pragma unroll
    for (int j = 0; j < 2; ++j) {
        if (j == 0) {   // prefetch pair 1 before computing pair 0
            const unsigned* pn = base + PIMG;
#pragma unroll
            for (int r = 0; r < 3; ++r) {
                uint4 a0 = *reinterpret_cast<const uint4*>(pn + r * 36);
                uint4 a1 = *reinterpret_cast<const uint4*>(pn + r * 36 + 4);
                uint4 a2 = *reinterpret_cast<const uint4*>(pn + r * 36 + 8);
                p[1][r][0] = a0.x; p[1][r][1]  = a0.y; p[1][r][2]  = a0.z; p[1][r][3]  = a0.w;
                p[1][r][4] = a1.x; p[1][r][5]  = a1.y; p[1][r][6]  = a1.z; p[1][r][7]  = a1.w;
                p[1][r][8] = a2.x; p[1][r][9]  = a2.y; p[1][r][10] = a2.z; p[1][r][11] = a2.w;
            }
        }
        const int pr = cq * 2 + j;
#pragma unroll
        for (int oo = 0; oo < 2; ++oo) {
            uint4 wa = *reinterpret_cast<const uint4*>(&wlds[oo][pr][0]);
            uint4 wb = *reinterpret_cast<const uint4*>(&wlds[oo][pr][4]);
            unsigned w8 = wlds[oo][pr][8];
            unsigned wv[9] = {wa.x, wa.y, wa.z, wa.w,
                              wb.x, wb.y, wb.z, wb.w, w8};
#pragma unroll
            for (int kh = 0; kh < 3; ++kh)
#pragma unroll
                for (int kw = 0; kw < 3; ++kw) {
                    unsigned ww = wv[kh * 3 + kw];
#pragma unroll
                    for (int xi = 0; xi < 8; ++xi)
                        acc[oo][xi] = sad16(p[j][kh][xi + kw], ww, acc[oo][xi]);
                }
        }
    }

    // ---- cq reduction via LDS ----
    {
        unsigned* dst = &red[cq][pos][0];
        *reinterpret_cast<uint4*>(dst + 0)  = make_uint4(acc[0][0], acc[0][1], acc[0][2], acc[0][3]);
        *reinterpret_cast<uint4*>(dst + 4)  = make_uint4(acc[0][4], acc[0][5], acc[0][6], acc[0][7]);
        *reinterpret_cast<uint4*>(dst + 8)  = make_uint4(acc[1][0], acc[1][1], acc[1][2], acc[1][3]);
        *reinterpret_cast<uint4*>(dst + 12) = make_uint4(acc[1][4], acc[1][5], acc[1][6], acc[1][7]);
    }
    __syncthreads();

    const int oo2 = t >> 7;
    const int s   = t & 127;
    const int yy2 = s >> 5;
    const int xx2 = s & 31;
    const int pp  = yy2 * 4 + (xx2 >> 3);
    const int z   = (oo2 << 3) | (xx2 & 7);
    unsigned total = 0;
#pragma unroll
    for (int q = 0; q < 16; ++q) total += red[q][pp][z];

    const int o    = og * 2 + oo2;
    const int gy   = sp * 4 + yy2;
    const float accf = (float)total;

    if (MODE == 0) {
        float a2 = fmaxf(fmaf(accf, bn2c[o], bn2c[o + 64]), 0.f);
        unsigned short qv = (unsigned short)(int)fmaf(a2, QSC, QBIAS_F);
        size_t widx = (size_t)(b * 32 + (o >> 1)) * PIMG + (gy + 1) * 36 + (xx2 + 1);
        reinterpret_cast<unsigned short*>(qout)[widx * 2 + (o & 1)] = qv;
    } else {
        float v = -accf * QINV;
        fout[((b * 64 + o) * 32 + gy) * 32 + xx2] = v;
        float sum = v;
#pragma unroll
        for (int off = 32; off > 0; off >>= 1)
            sum += __shfl_down(sum, off, 64);
        if ((t & 63) == 0) atomicAdd(&sbuf[b * 64 + o], sum);
    }
}

// ---------------------------------------------------------------------------
// SE gate + apply + shortcut. 256 blocks (one per b,o image) x 256 threads.
// ---------------------------------------------------------------------------
__global__ __launch_bounds__(256) void gate_kernel(
    const float* __restrict__ out2, const float* __restrict__ x,
    const float* __restrict__ sbuf,
    const float* __restrict__ fc1w, const float* __restrict__ fc1b,
    const float* __restrict__ fc2w, const float* __restrict__ fc2b,
    float* __restrict__ out)
{
    const int bo = blockIdx.x;
    const int b  = bo >> 6;
    const int o  = bo & 63;
    const int t  = threadIdx.x;

    __shared__ float ss[64];
    if (t < 64) ss[t] = sbuf[b * 64 + t] * (1.f / 1024.f);
    __syncthreads();

    float h[4];
#pragma unroll
    for (int j = 0; j < 4; ++j) {
        float a = fc1b[j];
#pragma unroll
        for (int c = 0; c < 64; ++c) a += ss[c] * fc1w[j * 64 + c];
        h[j] = fmaxf(a, 0.f);
    }
    float zz = fc2b[o];
#pragma unroll
    for (int j = 0; j < 4; ++j) zz += h[j] * fc2w[o * 4 + j];
    float g = 1.f / (1.f + __expf(-zz));

    const int base = bo * 1024 + t * 4;
    float4 v  = *reinterpret_cast<const float4*>(out2 + base);
    float4 xv = *reinterpret_cast<const float4*>(x + base);
    float4 r;
    r.x = v.x * g + xv.x;
    r.y = v.y * g + xv.y;
    r.z = v.z * g + xv.z;
    r.w = v.w * g + xv.w;
    *reinterpret_cast<float4*>(out + base) = r;
}

// ---------------------------------------------------------------------------
extern "C" void kernel_launch(void* const* d_in, const int* in_sizes, int n_in,
                              void* d_out, int out_size, void* d_ws, size_t ws_size,
                              hipStream_t stream)
{
    const float* x    = (const float*)d_in[0];
    const float* bn1g = (const float*)d_in[1];
    const float* bn1b = (const float*)d_in[2];
    const float* bn1m = (const float*)d_in[3];
    const float* bn1v = (const float*)d_in[4];
    const float* w1   = (const float*)d_in[5];
    const float* bn2g = (const float*)d_in[6];
    const float* bn2b = (const float*)d_in[7];
    const float* bn2m = (const float*)d_in[8];
    const float* bn2v = (const float*)d_in[9];
    const float* w2   = (const float*)d_in[10];
    const float* fc1w = (const float*)d_in[11];
    const float* fc1b = (const float*)d_in[12];
    const float* fc2w = (const float*)d_in[13];
    const float* fc2b = (const float*)d_in[14];

    unsigned* ws     = (unsigned*)d_ws;
    unsigned* qxp    = ws;                              // PPADN
    unsigned* qout1p = ws + PPADN;                      // PPADN
    float*    out2   = (float*)(ws + 2 * PPADN);        // NELEM
    unsigned* qw1p   = ws + 2 * PPADN + NELEM;          // NPAIRW
    unsigned* qw2p   = ws + 2 * PPADN + NELEM + NPAIRW; // NPAIRW
    float*    bn2c   = (float*)(ws + 2 * PPADN + NELEM + 2 * NPAIRW);        // 128
    float*    sbuf   = (float*)(ws + 2 * PPADN + NELEM + 2 * NPAIRW + 128);  // 256

    // segments: NPAIR + NPAIRW + NPAIRW + 64 + 256 = 185,152 -> 724 blocks
    prep_kernel<<<724, 256, 0, stream>>>(x, bn1g, bn1b, bn1m, bn1v, w1,
                                         bn2g, bn2b, bn2m, bn2v, w2,
                                         qxp, qout1p, qw1p, qw2p, bn2c, sbuf);
    adder_kernel<0><<<1024, 256, 0, stream>>>(qxp,    qw1p, bn2c, qout1p, nullptr, nullptr);
    adder_kernel<1><<<1024, 256, 0, stream>>>(qout1p, qw2p, nullptr, nullptr, out2, sbuf);
    gate_kernel<<<256, 256, 0, stream>>>(out2, x, sbuf, fc1w, fc1b, fc2w, fc2b,
                                         (float*)d_out);
}